// Round 1
// baseline (73.281 us; speedup 1.0000x reference)
//
#include <hip/hip_runtime.h>

#define B_SZ 16
#define NPTS 4096
#define BLK  256

// One block = (direction, batch, chunk of 256 "own" points).
// Stages all 4096 opposite points into LDS as (-2x, -2y, -2z, |t|^2),
// so each pair costs 3 fma + 1 min; |p|^2 is added after the min.
__global__ __launch_bounds__(BLK) void chamfer_kernel(
    const float* __restrict__ pred, const float* __restrict__ target,
    float* __restrict__ out)
{
    __shared__ float4 sOpp[NPTS];  // 64 KB exactly

    const int dir = blockIdx.y;
    const float* own = (dir == 0) ? pred : target;
    const float* opp = (dir == 0) ? target : pred;

    const int b     = blockIdx.x >> 4;   // 16 chunks per batch
    const int chunk = blockIdx.x & 15;
    const int tid   = threadIdx.x;

    // ---- stage opposite set for batch b into LDS (packed) ----
    const float* oppB = opp + (size_t)b * NPTS * 3;
    for (int j = tid; j < NPTS; j += BLK) {
        float x = oppB[3 * j + 0];
        float y = oppB[3 * j + 1];
        float z = oppB[3 * j + 2];
        sOpp[j] = make_float4(-2.0f * x, -2.0f * y, -2.0f * z,
                              fmaf(z, z, fmaf(y, y, x * x)));
    }
    __syncthreads();

    // ---- own point for this thread ----
    const int i = chunk * BLK + tid;
    const float* op = own + ((size_t)b * NPTS + i) * 3;
    const float px = op[0], py = op[1], pz = op[2];
    const float p2 = fmaf(pz, pz, fmaf(py, py, px * px));

    // ---- min over all opposite points: 4 independent chains for ILP ----
    float m0 = 1e30f, m1 = 1e30f, m2 = 1e30f, m3 = 1e30f;
    for (int j = 0; j < NPTS; j += 8) {
        float4 t0 = sOpp[j + 0];
        float4 t1 = sOpp[j + 1];
        float4 t2 = sOpp[j + 2];
        float4 t3 = sOpp[j + 3];
        float4 t4 = sOpp[j + 4];
        float4 t5 = sOpp[j + 5];
        float4 t6 = sOpp[j + 6];
        float4 t7 = sOpp[j + 7];
        m0 = fminf(m0, fmaf(t0.x, px, fmaf(t0.y, py, fmaf(t0.z, pz, t0.w))));
        m1 = fminf(m1, fmaf(t1.x, px, fmaf(t1.y, py, fmaf(t1.z, pz, t1.w))));
        m2 = fminf(m2, fmaf(t2.x, px, fmaf(t2.y, py, fmaf(t2.z, pz, t2.w))));
        m3 = fminf(m3, fmaf(t3.x, px, fmaf(t3.y, py, fmaf(t3.z, pz, t3.w))));
        m0 = fminf(m0, fmaf(t4.x, px, fmaf(t4.y, py, fmaf(t4.z, pz, t4.w))));
        m1 = fminf(m1, fmaf(t5.x, px, fmaf(t5.y, py, fmaf(t5.z, pz, t5.w))));
        m2 = fminf(m2, fmaf(t6.x, px, fmaf(t6.y, py, fmaf(t6.z, pz, t6.w))));
        m3 = fminf(m3, fmaf(t7.x, px, fmaf(t7.y, py, fmaf(t7.z, pz, t7.w))));
    }
    float v = fminf(fminf(m0, m1), fminf(m2, m3)) + p2;

    // ---- block-sum: wave shuffle reduce, then LDS (reused) combine ----
    for (int off = 32; off > 0; off >>= 1)
        v += __shfl_down(v, off, 64);

    __syncthreads();               // everyone done reading sOpp
    float* red = (float*)sOpp;     // reuse LDS for 4 wave partials
    if ((tid & 63) == 0) red[tid >> 6] = v;
    __syncthreads();
    if (tid == 0) {
        float s = (red[0] + red[1]) + (red[2] + red[3]);
        // loss = sumX/(B*N) + sumY/(B*M); N == M so one scale works
        atomicAdd(out, s * (1.0f / ((float)B_SZ * (float)NPTS)));
    }
}

extern "C" void kernel_launch(void* const* d_in, const int* in_sizes, int n_in,
                              void* d_out, int out_size, void* d_ws, size_t ws_size,
                              hipStream_t stream) {
    const float* pred   = (const float*)d_in[0];
    const float* target = (const float*)d_in[1];
    float* out = (float*)d_out;

    hipMemsetAsync(out, 0, sizeof(float), stream);

    // grid.x = B * (NPTS / BLK) = 16 * 16 = 256 ; grid.y = 2 directions
    dim3 grid(B_SZ * (NPTS / BLK), 2);
    chamfer_kernel<<<grid, BLK, 0, stream>>>(pred, target, out);
}

// Round 2
// 59.007 us; speedup vs baseline: 1.2419x; 1.2419x over previous
//
#include <hip/hip_runtime.h>

#define B_SZ   16
#define NPTS   4096
#define BLK    256
#define QPTS   1024                 // opposite points per quarter
#define OWN_PB 1024                 // own points per block (4 per thread)
#define TOT    (2 * B_SZ * NPTS)    // 131072 own-points across both directions

// ---------------- main kernel: partial mins over one opp-quarter -------------
// grid.x = B * 4(own chunks) * 4(quarters) = 256, grid.y = 2 (direction)
__global__ __launch_bounds__(BLK) void chamfer_part(
    const float* __restrict__ pred, const float* __restrict__ target,
    float* __restrict__ ws)
{
    __shared__ float4 sOpp[QPTS];   // 16 KB: (-2x,-2y,-2z,|t|^2)

    const int dir = blockIdx.y;
    const float* own = (dir == 0) ? pred : target;
    const float* opp = (dir == 0) ? target : pred;

    const int bx    = blockIdx.x;
    const int b     = bx >> 4;
    const int chunk = (bx >> 2) & 3;
    const int q     = bx & 3;
    const int tid   = threadIdx.x;

    // stage this quarter of the opposite set
    const float* oppB = opp + ((size_t)b * NPTS + q * QPTS) * 3;
    for (int j = tid; j < QPTS; j += BLK) {
        float x = oppB[3 * j + 0];
        float y = oppB[3 * j + 1];
        float z = oppB[3 * j + 2];
        sOpp[j] = make_float4(-2.0f * x, -2.0f * y, -2.0f * z,
                              fmaf(z, z, fmaf(y, y, x * x)));
    }
    __syncthreads();

    // 4 own points per thread (strided for coalescing)
    float px[4], py[4], pz[4], p2[4], m[4];
    #pragma unroll
    for (int k = 0; k < 4; ++k) {
        const int i = chunk * OWN_PB + k * BLK + tid;
        const float* op = own + ((size_t)b * NPTS + i) * 3;
        px[k] = op[0]; py[k] = op[1]; pz[k] = op[2];
        p2[k] = fmaf(pz[k], pz[k], fmaf(py[k], py[k], px[k] * px[k]));
        m[k]  = 1e30f;
    }

    // min over the quarter: 1 ds_read_b128 amortized over 4 own points
    for (int j = 0; j < QPTS; j += 4) {
        float4 t0 = sOpp[j + 0];
        float4 t1 = sOpp[j + 1];
        float4 t2 = sOpp[j + 2];
        float4 t3 = sOpp[j + 3];
        #pragma unroll
        for (int k = 0; k < 4; ++k) {
            m[k] = fminf(m[k], fmaf(t0.x, px[k], fmaf(t0.y, py[k], fmaf(t0.z, pz[k], t0.w))));
            m[k] = fminf(m[k], fmaf(t1.x, px[k], fmaf(t1.y, py[k], fmaf(t1.z, pz[k], t1.w))));
            m[k] = fminf(m[k], fmaf(t2.x, px[k], fmaf(t2.y, py[k], fmaf(t2.z, pz[k], t2.w))));
            m[k] = fminf(m[k], fmaf(t3.x, px[k], fmaf(t3.y, py[k], fmaf(t3.z, pz[k], t3.w))));
        }
    }

    // ws layout: [q][dir][b][own]  -> fully coalesced writes
    float* wq = ws + (size_t)q * TOT + ((size_t)dir * B_SZ + b) * NPTS;
    #pragma unroll
    for (int k = 0; k < 4; ++k) {
        const int i = chunk * OWN_PB + k * BLK + tid;
        wq[i] = m[k] + p2[k];   // +p2 commutes with the cross-quarter min
    }
}

// ---------------- combine kernel: min over quarters, mean-reduce -------------
__global__ __launch_bounds__(BLK) void chamfer_combine(
    const float* __restrict__ ws, float* __restrict__ out)
{
    const int idx = blockIdx.x * BLK + threadIdx.x;   // 0 .. TOT-1
    float v = fminf(fminf(ws[idx],           ws[TOT + idx]),
                    fminf(ws[2 * TOT + idx], ws[3 * TOT + idx]));

    for (int off = 32; off > 0; off >>= 1)
        v += __shfl_down(v, off, 64);

    __shared__ float red[4];
    const int tid = threadIdx.x;
    if ((tid & 63) == 0) red[tid >> 6] = v;
    __syncthreads();
    if (tid == 0) {
        float s = (red[0] + red[1]) + (red[2] + red[3]);
        atomicAdd(out, s * (1.0f / ((float)B_SZ * (float)NPTS)));
    }
}

// ---------------- fallback (round-1 kernel) if ws too small ------------------
__global__ __launch_bounds__(BLK) void chamfer_kernel(
    const float* __restrict__ pred, const float* __restrict__ target,
    float* __restrict__ out)
{
    __shared__ float4 sOpp[NPTS];

    const int dir = blockIdx.y;
    const float* own = (dir == 0) ? pred : target;
    const float* opp = (dir == 0) ? target : pred;

    const int b     = blockIdx.x >> 4;
    const int chunk = blockIdx.x & 15;
    const int tid   = threadIdx.x;

    const float* oppB = opp + (size_t)b * NPTS * 3;
    for (int j = tid; j < NPTS; j += BLK) {
        float x = oppB[3 * j + 0];
        float y = oppB[3 * j + 1];
        float z = oppB[3 * j + 2];
        sOpp[j] = make_float4(-2.0f * x, -2.0f * y, -2.0f * z,
                              fmaf(z, z, fmaf(y, y, x * x)));
    }
    __syncthreads();

    const int i = chunk * BLK + tid;
    const float* op = own + ((size_t)b * NPTS + i) * 3;
    const float px = op[0], py = op[1], pz = op[2];
    const float p2 = fmaf(pz, pz, fmaf(py, py, px * px));

    float m0 = 1e30f, m1 = 1e30f, m2 = 1e30f, m3 = 1e30f;
    for (int j = 0; j < NPTS; j += 8) {
        float4 t0 = sOpp[j + 0];
        float4 t1 = sOpp[j + 1];
        float4 t2 = sOpp[j + 2];
        float4 t3 = sOpp[j + 3];
        float4 t4 = sOpp[j + 4];
        float4 t5 = sOpp[j + 5];
        float4 t6 = sOpp[j + 6];
        float4 t7 = sOpp[j + 7];
        m0 = fminf(m0, fmaf(t0.x, px, fmaf(t0.y, py, fmaf(t0.z, pz, t0.w))));
        m1 = fminf(m1, fmaf(t1.x, px, fmaf(t1.y, py, fmaf(t1.z, pz, t1.w))));
        m2 = fminf(m2, fmaf(t2.x, px, fmaf(t2.y, py, fmaf(t2.z, pz, t2.w))));
        m3 = fminf(m3, fmaf(t3.x, px, fmaf(t3.y, py, fmaf(t3.z, pz, t3.w))));
        m0 = fminf(m0, fmaf(t4.x, px, fmaf(t4.y, py, fmaf(t4.z, pz, t4.w))));
        m1 = fminf(m1, fmaf(t5.x, px, fmaf(t5.y, py, fmaf(t5.z, pz, t5.w))));
        m2 = fminf(m2, fmaf(t6.x, px, fmaf(t6.y, py, fmaf(t6.z, pz, t6.w))));
        m3 = fminf(m3, fmaf(t7.x, px, fmaf(t7.y, py, fmaf(t7.z, pz, t7.w))));
    }
    float v = fminf(fminf(m0, m1), fminf(m2, m3)) + p2;

    for (int off = 32; off > 0; off >>= 1)
        v += __shfl_down(v, off, 64);

    __syncthreads();
    float* red = (float*)sOpp;
    if ((tid & 63) == 0) red[tid >> 6] = v;
    __syncthreads();
    if (tid == 0) {
        float s = (red[0] + red[1]) + (red[2] + red[3]);
        atomicAdd(out, s * (1.0f / ((float)B_SZ * (float)NPTS)));
    }
}

extern "C" void kernel_launch(void* const* d_in, const int* in_sizes, int n_in,
                              void* d_out, int out_size, void* d_ws, size_t ws_size,
                              hipStream_t stream) {
    const float* pred   = (const float*)d_in[0];
    const float* target = (const float*)d_in[1];
    float* out = (float*)d_out;

    hipMemsetAsync(out, 0, sizeof(float), stream);

    const size_t ws_needed = (size_t)4 * TOT * sizeof(float);  // 2 MB
    if (ws_size >= ws_needed) {
        float* ws = (float*)d_ws;
        dim3 grid1(B_SZ * 4 * 4, 2);          // 256 x 2 = 512 blocks
        chamfer_part<<<grid1, BLK, 0, stream>>>(pred, target, ws);
        chamfer_combine<<<TOT / BLK, BLK, 0, stream>>>(ws, out);
    } else {
        dim3 grid(B_SZ * (NPTS / BLK), 2);
        chamfer_kernel<<<grid, BLK, 0, stream>>>(pred, target, out);
    }
}